// Round 3
// baseline (27.066 us; speedup 1.0000x reference)
//
#include <hip/hip_runtime.h>
#include <cstdint>

#define TPB 256
#define LOG2E 1.4426950408889634f
#define LN2   0.69314718055994531f

__global__ __launch_bounds__(TPB, 4)
void pl_main(const float* __restrict__ scores,
             const int* __restrict__ ranks,
             const int* __restrict__ mask,
             float* __restrict__ partials,
             int B)
{
    const int tid = threadIdx.x;
    const int row = blockIdx.x * TPB + tid;

    // thread t owns column t: bank t%32 for every access (writes, gathers)
    // -> conflict-free (2 lanes/bank is free), and no barrier ever needed.
    __shared__ float eb[32 * TPB];   // 32 KB

    float per_row = 0.0f, cnt = 0.0f;

    if (row < B) {
        const float4* sp = reinterpret_cast<const float4*>(scores) + (size_t)row * 8;
        const int4*   rp = reinterpret_cast<const int4*>(ranks)  + (size_t)row * 8;
        const int4*   mp = reinterpret_cast<const int4*>(mask)   + (size_t)row * 8;

        // Issue score loads FIRST; they are consumed only after the sort,
        // so their latency hides under the bitonic network (keys only).
        float4 sv[8];
        #pragma unroll
        for (int c = 0; c < 8; ++c) sv[c] = sp[c];

        // key = mask*1024 + rank*32 + j : unique 11-bit, stable-sort order;
        // key & 31 == original slot j; valid keys (<1024) sort to the front.
        unsigned K[32];
        int nm = 0;
        #pragma unroll
        for (int c = 0; c < 8; ++c) {
            const int4 rv = rp[c];
            const int4 qv = mp[c];
            const int j = c * 4;
            K[j+0] = (unsigned)((qv.x << 10) + (rv.x << 5) + (j+0));
            K[j+1] = (unsigned)((qv.y << 10) + (rv.y << 5) + (j+1));
            K[j+2] = (unsigned)((qv.z << 10) + (rv.z << 5) + (j+2));
            K[j+3] = (unsigned)((qv.w << 10) + (rv.w << 5) + (j+3));
            nm += (qv.x + qv.y) + (qv.z + qv.w);
        }
        const int n = 32 - nm;

        // key-only bitonic sort, ascending; fully unrolled -> 2 VALU/comparator
        #pragma unroll
        for (int kk = 2; kk <= 32; kk <<= 1) {
            #pragma unroll
            for (int jj = kk >> 1; jj > 0; jj >>= 1) {
                #pragma unroll
                for (int i = 0; i < 32; ++i) {
                    const int l = i ^ jj;
                    if (l > i) {
                        const unsigned a = K[i], b = K[l];
                        const unsigned mn = a < b ? a : b;
                        const unsigned mh = a < b ? b : a;
                        if ((i & kk) == 0) { K[i] = mn; K[l] = mh; }
                        else               { K[i] = mh; K[l] = mn; }
                    }
                }
            }
        }

        // row max over ALL 32 entries — the shift cancels exactly in
        // log2(T_p) - log2(e_p), it only sets the numeric range of exp.
        float cm[8];
        #pragma unroll
        for (int c = 0; c < 8; ++c)
            cm[c] = fmaxf(fmaxf(sv[c].x, sv[c].y), fmaxf(sv[c].z, sv[c].w));
        const float mx = fmaxf(fmaxf(fmaxf(cm[0], cm[1]), fmaxf(cm[2], cm[3])),
                               fmaxf(fmaxf(cm[4], cm[5]), fmaxf(cm[6], cm[7])));
        const float nml = -mx * LOG2E;

        // e_j for ALL slots, unmasked (masked slots land at p>=n and are
        // excluded there); write into own LDS column.
        #pragma unroll
        for (int c = 0; c < 8; ++c) {
            const int j = c * 4;
            eb[(j+0)*TPB + tid] = __builtin_amdgcn_exp2f(__builtin_fmaf(sv[c].x, LOG2E, nml));
            eb[(j+1)*TPB + tid] = __builtin_amdgcn_exp2f(__builtin_fmaf(sv[c].y, LOG2E, nml));
            eb[(j+2)*TPB + tid] = __builtin_amdgcn_exp2f(__builtin_fmaf(sv[c].z, LOG2E, nml));
            eb[(j+3)*TPB + tid] = __builtin_amdgcn_exp2f(__builtin_fmaf(sv[c].w, LOG2E, nml));
        }

        // gather e in sorted order (32 independent ds_reads, one wait)
        float es[32];
        #pragma unroll
        for (int p = 0; p < 32; ++p)
            es[p] = eb[(K[p] & 31u) * TPB + tid];

        // loss = ln2 * sum_{p<n} (log2 T_p - log2 e_p), T_p = suffix sum.
        // Grouped 4-wide products keep everything safely in f32 range.
        float t = 0.0f, lsum = 0.0f;
        #pragma unroll
        for (int g = 7; g >= 0; --g) {
            float pT = 1.0f, pE = 1.0f;
            #pragma unroll
            for (int q = 3; q >= 0; --q) {
                const int p = 4*g + q;
                const bool v = (p < n);          // literal vs per-thread scalar
                t  += v ? es[p] : 0.0f;
                pT *= v ? t     : 1.0f;
                pE *= v ? es[p] : 1.0f;
            }
            lsum += __builtin_amdgcn_logf(pT) - __builtin_amdgcn_logf(pE);  // hw log2
        }

        if (n >= 2) {
            per_row = (LN2 * lsum) / (float)n;
            cnt = 1.0f;
        }
    }

    // wave reduce, then combine the block's 4 waves
    #pragma unroll
    for (int d = 32; d >= 1; d >>= 1) {
        per_row += __shfl_xor(per_row, d, 64);
        cnt     += __shfl_xor(cnt,     d, 64);
    }
    __shared__ float rbuf[8];
    if ((tid & 63) == 0) {
        rbuf[(tid >> 6)]     = per_row;
        rbuf[4 + (tid >> 6)] = cnt;
    }
    __syncthreads();
    if (tid == 0) {
        partials[2*blockIdx.x]     = (rbuf[0] + rbuf[1]) + (rbuf[2] + rbuf[3]);
        partials[2*blockIdx.x + 1] = (rbuf[4] + rbuf[5]) + (rbuf[6] + rbuf[7]);
    }
}

__global__ __launch_bounds__(256)
void pl_final(const float* __restrict__ partials, int nb, float* __restrict__ out)
{
    const int tid = threadIdx.x;
    float s = 0.0f, c = 0.0f;
    for (int i = tid; i < nb; i += 256) {
        s += partials[2*i];
        c += partials[2*i + 1];
    }
    #pragma unroll
    for (int d = 32; d >= 1; d >>= 1) {
        s += __shfl_xor(s, d, 64);
        c += __shfl_xor(c, d, 64);
    }
    __shared__ float sb[8];
    if ((tid & 63) == 0) {
        sb[tid >> 6]       = s;
        sb[4 + (tid >> 6)] = c;
    }
    __syncthreads();
    if (tid == 0) {
        const float S = sb[0] + sb[1] + sb[2] + sb[3];
        const float C = sb[4] + sb[5] + sb[6] + sb[7];
        out[0] = S / fmaxf(C, 1.0f);
    }
}

extern "C" void kernel_launch(void* const* d_in, const int* in_sizes, int n_in,
                              void* d_out, int out_size, void* d_ws, size_t ws_size,
                              hipStream_t stream)
{
    const float* scores = (const float*)d_in[0];
    const int*   ranks  = (const int*)d_in[1];
    const int*   mask   = (const int*)d_in[2];

    const int B  = in_sizes[0] / 32;
    const int nb = (B + TPB - 1) / TPB;

    float* partials = (float*)d_ws;  // nb * 2 floats

    pl_main<<<nb, TPB, 0, stream>>>(scores, ranks, mask, partials, B);
    pl_final<<<1, 256, 0, stream>>>(partials, nb, (float*)d_out);
}